// Round 2
// baseline (1279.235 us; speedup 1.0000x reference)
//
#include <hip/hip_runtime.h>

#define DD 192
#define HH 224
#define WW 192
#define HWN (HH*WW)              // 43008
#define PLANE ((size_t)DD*HWN)   // 8257536
#define NHC 8
#define HCH 28                   // 8 * 28 = 224
#define NPART (DD*NHC)           // 1536
#define SEG 32

// ---------------- K1: 5 products + D-axis 9-tap box sum ----------------
// thread = one (h,w) column; register ring of 9 per product, running sums.
// Proven BW-bound (~6.2 TB/s): unchanged from round 0.
__global__ __launch_bounds__(256) void k1_dsum(
    const float* __restrict__ I, const float* __restrict__ J,
    float* __restrict__ F, int d0, int d1, int cd_total)
{
    int c = blockIdx.x * 256 + threadIdx.x;          // column in [0, HWN)
    int sd0 = d0 + blockIdx.y * SEG;                 // this block's d-segment
    int sd1 = sd0 + SEG; if (sd1 > d1) sd1 = d1;
    if (sd0 >= d1) return;

    float rA[9], rB[9], rC[9], rD_[9], rE[9];
    float sA=0.f, sB=0.f, sC=0.f, sD=0.f, sE=0.f;
#pragma unroll
    for (int k = 0; k < 9; ++k) { rA[k]=0.f; rB[k]=0.f; rC[k]=0.f; rD_[k]=0.f; rE[k]=0.f; }

    const int start  = sd0 - 4;
    const int nsteps = (sd1 - sd0) + 8;
    const size_t fs  = (size_t)cd_total * HWN;

    for (int base = 0; base < nsteps; base += 9) {
#pragma unroll
        for (int k = 0; k < 9; ++k) {
            int s = base + k;
            if (s < nsteps) {
                int din = start + s;
                float vI = 0.f, vJ = 0.f;
                if (din >= 0 && din < DD) {
                    vI = I[(size_t)din * HWN + c];
                    vJ = J[(size_t)din * HWN + c];
                }
                float vC = vI * vI, vD = vJ * vJ, vE = vI * vJ;
                sA += vI - rA[k];  rA[k]  = vI;
                sB += vJ - rB[k];  rB[k]  = vJ;
                sC += vC - rC[k];  rC[k]  = vC;
                sD += vD - rD_[k]; rD_[k] = vD;
                sE += vE - rE[k];  rE[k]  = vE;
                int dout = din - 4;
                if (dout >= sd0 && dout < sd1) {
                    size_t o = (size_t)(dout - d0) * HWN + c;
                    F[o]        = sA;
                    F[fs + o]   = sB;
                    F[2*fs + o] = sC;
                    F[3*fs + o] = sD;
                    F[4*fs + o] = sE;
                }
            }
        }
    }
}

// ---------------- K2: W-axis box sum (LDS) + H-axis box sum (reg ring) +
//   NCC math + deterministic block partial.
//   v2: NHC=8 (2x blocks), prefetch-over-raw-barrier, 1 barrier/step,
//       double-buffered LDS rows, fully unrolled 36 steps. ----------------
__global__ __launch_bounds__(192) void k2_whsum(
    const float* __restrict__ F, double* __restrict__ partials,
    int d0, int CD)
{
    int bx   = blockIdx.x;
    int drel = bx >> 3;
    int hc   = bx & 7;
    int d    = d0 + drel;
    int w    = threadIdx.x;          // 0..191
    int h0   = hc * HCH;

    __shared__ float rows[2 * 5 * 200];   // [par][field][4pad + 192 + 4pad]
    if (w < 4) {
#pragma unroll
        for (int b = 0; b < 2; ++b)
#pragma unroll
            for (int f = 0; f < 5; ++f) {
                rows[b*1000 + f*200 + w]       = 0.f;
                rows[b*1000 + f*200 + 196 + w] = 0.f;
            }
    }
    // pad writes ordered before first reads by the in-loop lgkmcnt+barrier

    const size_t fs = (size_t)CD * HWN;
    const float* __restrict__ F0 = F;
    const float* __restrict__ F1 = F + fs;
    const float* __restrict__ F2 = F + 2*fs;
    const float* __restrict__ F3 = F + 3*fs;
    const float* __restrict__ F4 = F + 4*fs;
    const size_t cbase = (size_t)drel * HWN + (size_t)w;

    float rS[5][9];
    float S[5] = {0.f,0.f,0.f,0.f,0.f};
#pragma unroll
    for (int f = 0; f < 5; ++f)
#pragma unroll
        for (int k = 0; k < 9; ++k) rS[f][k] = 0.f;

    float acc = 0.f;

    // preload s=0 (hin = h0-4; always < HH)
    float v0=0.f, v1=0.f, v2=0.f, v3=0.f, v4=0.f;
    {
        int hin = h0 - 4;
        if (hin >= 0) {
            size_t o = cbase + (size_t)hin * WW;
            v0=F0[o]; v1=F1[o]; v2=F2[o]; v3=F3[o]; v4=F4[o];
        }
    }

#pragma unroll
    for (int base = 0; base < 36; base += 9) {
#pragma unroll
        for (int k = 0; k < 9; ++k) {
            const int s   = base + k;          // compile-time (full unroll)
            const int par = s & 1;
            float* buf = &rows[par * 1000];

            // stage current row (values for step s)
            buf[0*200 + 4 + w] = v0;
            buf[1*200 + 4 + w] = v1;
            buf[2*200 + 4 + w] = v2;
            buf[3*200 + 4 + w] = v3;
            buf[4*200 + 4 + w] = v4;

            // prefetch step s+1 (stays in flight across the raw barrier)
            if (s < 35) {
                int hin = h0 - 3 + s;
                float t0=0.f,t1=0.f,t2=0.f,t3=0.f,t4=0.f;
                if (hin >= 0 && hin < HH) {
                    size_t o = cbase + (size_t)hin * WW;
                    t0=F0[o]; t1=F1[o]; t2=F2[o]; t3=F3[o]; t4=F4[o];
                }
                v0=t0; v1=t1; v2=t2; v3=t3; v4=t4;
            }

            asm volatile("s_waitcnt lgkmcnt(0)" ::: "memory");  // my ds_writes done
            __builtin_amdgcn_s_barrier();                        // no vmcnt drain
            __builtin_amdgcn_sched_barrier(0);                   // no read hoisting

#pragma unroll
            for (int f = 0; f < 5; ++f) {
                float t = 0.f;
#pragma unroll
                for (int j = 0; j < 9; ++j) t += buf[f*200 + w + j];
                S[f] += t - rS[f][k];
                rS[f][k] = t;
            }
            if (s >= 8) {
                const float inv = 1.0f / 729.0f;
                float cross = S[4] - S[0] * S[1] * inv;
                float varI  = S[2] - S[0] * S[0] * inv;
                float varJ  = S[3] - S[1] * S[1] * inv;
                acc += cross * cross / (varI * varJ + 1e-5f);
            }
        }
    }

    __shared__ float red[192];
    red[w] = acc;
    __syncthreads();
#pragma unroll
    for (int off = 96; off >= 3; off >>= 1) {
        if (w < off) red[w] += red[w + off];
        __syncthreads();
    }
    if (w == 0) partials[d * NHC + hc] = (double)(red[0] + red[1] + red[2]);
}

// ---------------- K3: final reduction of 1536 partials ----------------
__global__ __launch_bounds__(256) void k3_reduce(
    const double* __restrict__ partials, float* __restrict__ out)
{
    __shared__ double red[256];
    int t = threadIdx.x;
    double a = 0.0;
    for (int i = t; i < NPART; i += 256) a += partials[i];
    red[t] = a;
    __syncthreads();
    for (int off = 128; off > 0; off >>= 1) {
        if (t < off) red[t] += red[t + off];
        __syncthreads();
    }
    if (t == 0) out[0] = (float)(-red[0] / (double)PLANE);
}

extern "C" void kernel_launch(void* const* d_in, const int* in_sizes, int n_in,
                              void* d_out, int out_size, void* d_ws, size_t ws_size,
                              hipStream_t stream)
{
    const float* I = (const float*)d_in[0];
    const float* J = (const float*)d_in[1];
    float* out = (float*)d_out;

    double* partials = (double*)d_ws;
    const size_t part_bytes = (size_t)NPART * sizeof(double);
    float* F = (float*)((char*)d_ws + part_bytes);

    // Largest d-chunk (divisor of 192) whose 5-field buffer fits in ws.
    static const int divs[13] = {192,96,64,48,32,24,16,12,8,6,4,2,1};
    int CD = 1;
    for (int i = 0; i < 13; ++i) {
        size_t need = part_bytes + 5ull * (size_t)divs[i] * HWN * sizeof(float);
        if (need <= ws_size) { CD = divs[i]; break; }
    }

    for (int d0 = 0; d0 < DD; d0 += CD) {
        int d1 = d0 + CD;
        int nseg = (CD + SEG - 1) / SEG;
        dim3 g1(HWN / 256, nseg);
        k1_dsum<<<g1, dim3(256), 0, stream>>>(I, J, F, d0, d1, CD);
        k2_whsum<<<dim3(CD * NHC), dim3(192), 0, stream>>>(F, partials, d0, CD);
    }
    k3_reduce<<<dim3(1), dim3(256), 0, stream>>>(partials, out);
}

// Round 3
// 152.338 us; speedup vs baseline: 8.3973x; 8.3973x over previous
//
#include <hip/hip_runtime.h>

#define DD 192
#define HH 224
#define WW 192
#define HWN (HH*WW)              // 43008
#define PLANE ((size_t)DD*HWN)   // 8257536
#define NHC 8
#define HCH 28                   // 8 * 28 = 224
#define NPART (DD*NHC)           // 1536
#define SEG 32

// ---------------- K1: 5 products + D-axis 9-tap box sum ----------------
// thread = one (h,w) column; register ring of 9 per product, running sums.
// Proven BW-bound (~6.2 TB/s): unchanged.
__global__ __launch_bounds__(256) void k1_dsum(
    const float* __restrict__ I, const float* __restrict__ J,
    float* __restrict__ F, int d0, int d1, int cd_total)
{
    int c = blockIdx.x * 256 + threadIdx.x;          // column in [0, HWN)
    int sd0 = d0 + blockIdx.y * SEG;                 // this block's d-segment
    int sd1 = sd0 + SEG; if (sd1 > d1) sd1 = d1;
    if (sd0 >= d1) return;

    float rA[9], rB[9], rC[9], rD_[9], rE[9];
    float sA=0.f, sB=0.f, sC=0.f, sD=0.f, sE=0.f;
#pragma unroll
    for (int k = 0; k < 9; ++k) { rA[k]=0.f; rB[k]=0.f; rC[k]=0.f; rD_[k]=0.f; rE[k]=0.f; }

    const int start  = sd0 - 4;
    const int nsteps = (sd1 - sd0) + 8;
    const size_t fs  = (size_t)cd_total * HWN;

    for (int base = 0; base < nsteps; base += 9) {
#pragma unroll
        for (int k = 0; k < 9; ++k) {
            int s = base + k;
            if (s < nsteps) {
                int din = start + s;
                float vI = 0.f, vJ = 0.f;
                if (din >= 0 && din < DD) {
                    vI = I[(size_t)din * HWN + c];
                    vJ = J[(size_t)din * HWN + c];
                }
                float vC = vI * vI, vD = vJ * vJ, vE = vI * vJ;
                sA += vI - rA[k];  rA[k]  = vI;
                sB += vJ - rB[k];  rB[k]  = vJ;
                sC += vC - rC[k];  rC[k]  = vC;
                sD += vD - rD_[k]; rD_[k] = vD;
                sE += vE - rE[k];  rE[k]  = vE;
                int dout = din - 4;
                if (dout >= sd0 && dout < sd1) {
                    size_t o = (size_t)(dout - d0) * HWN + c;
                    F[o]        = sA;
                    F[fs + o]   = sB;
                    F[2*fs + o] = sC;
                    F[3*fs + o] = sD;
                    F[4*fs + o] = sE;
                }
            }
        }
    }
}

// ---------------- K2: W-axis box sum (LDS) + H-axis box sum (reg ring) +
//   NCC math + deterministic block partial.
//   v3 = round-1 structure (no outer unroll, single LDS buffer, 2 barriers/
//   step) + NHC=8 + raw barriers (no vmcnt drain) + next-row prefetch.
__global__ __launch_bounds__(192) void k2_whsum(
    const float* __restrict__ F, double* __restrict__ partials,
    int d0, int CD)
{
    int bx   = blockIdx.x;
    int drel = bx >> 3;
    int hc   = bx & 7;
    int d    = d0 + drel;
    int w    = threadIdx.x;          // 0..191
    int h0   = hc * HCH;

    __shared__ float rows[5][200];   // 4 pad | 192 | 4 pad
    if (w < 4) {
#pragma unroll
        for (int f = 0; f < 5; ++f) { rows[f][w] = 0.f; rows[f][196 + w] = 0.f; }
    }
    // pad ds_writes ordered before first reads by the first in-loop
    // lgkmcnt(0)+barrier pair.

    const size_t fs = (size_t)CD * HWN;
    const float* __restrict__ F0 = F;
    const float* __restrict__ F1 = F + fs;
    const float* __restrict__ F2 = F + 2*fs;
    const float* __restrict__ F3 = F + 3*fs;
    const float* __restrict__ F4 = F + 4*fs;
    const size_t cbase = (size_t)drel * HWN + (size_t)w;

    float rS[5][9];
    float S[5] = {0.f,0.f,0.f,0.f,0.f};
#pragma unroll
    for (int f = 0; f < 5; ++f)
#pragma unroll
        for (int k = 0; k < 9; ++k) rS[f][k] = 0.f;

    float acc = 0.f;

    // preload row for s=0 (hin = h0-4, always < HH)
    float v0=0.f, v1=0.f, v2=0.f, v3=0.f, v4=0.f;
    {
        int hin = h0 - 4;
        if (hin >= 0) {
            size_t o = cbase + (size_t)hin * WW;
            v0=F0[o]; v1=F1[o]; v2=F2[o]; v3=F3[o]; v4=F4[o];
        }
    }

    for (int base = 0; base < 36; base += 9) {       // runtime loop: no bloat
#pragma unroll
        for (int k = 0; k < 9; ++k) {
            int s = base + k;

            // barrier A: everyone's reads of rows[] from previous step done
            asm volatile("s_waitcnt lgkmcnt(0)" ::: "memory");
            __builtin_amdgcn_s_barrier();
            __builtin_amdgcn_sched_barrier(0);

            // stage current row (values for step s)
            rows[0][4 + w] = v0;
            rows[1][4 + w] = v1;
            rows[2][4 + w] = v2;
            rows[3][4 + w] = v3;
            rows[4][4 + w] = v4;

            // prefetch step s+1 (global loads stay in flight across the
            // raw barrier below — no vmcnt drain)
            if (s < 35) {
                int hin = h0 - 3 + s;
                float t0=0.f,t1=0.f,t2=0.f,t3=0.f,t4=0.f;
                if (hin >= 0 && hin < HH) {
                    size_t o = cbase + (size_t)hin * WW;
                    t0=F0[o]; t1=F1[o]; t2=F2[o]; t3=F3[o]; t4=F4[o];
                }
                v0=t0; v1=t1; v2=t2; v3=t3; v4=t4;
            }

            // barrier B: my ds_writes visible to everyone
            asm volatile("s_waitcnt lgkmcnt(0)" ::: "memory");
            __builtin_amdgcn_s_barrier();
            __builtin_amdgcn_sched_barrier(0);

#pragma unroll
            for (int f = 0; f < 5; ++f) {
                float t = 0.f;
#pragma unroll
                for (int j = 0; j < 9; ++j) t += rows[f][w + j];
                S[f] += t - rS[f][k];
                rS[f][k] = t;
            }
            if (s >= 8) {
                const float inv = 1.0f / 729.0f;
                float cross = S[4] - S[0] * S[1] * inv;
                float varI  = S[2] - S[0] * S[0] * inv;
                float varJ  = S[3] - S[1] * S[1] * inv;
                acc += cross * cross / (varI * varJ + 1e-5f);
            }
        }
    }

    __shared__ float red[192];
    red[w] = acc;
    __syncthreads();
#pragma unroll
    for (int off = 96; off >= 3; off >>= 1) {
        if (w < off) red[w] += red[w + off];
        __syncthreads();
    }
    if (w == 0) partials[d * NHC + hc] = (double)(red[0] + red[1] + red[2]);
}

// ---------------- K3: final reduction of 1536 partials ----------------
__global__ __launch_bounds__(256) void k3_reduce(
    const double* __restrict__ partials, float* __restrict__ out)
{
    __shared__ double red[256];
    int t = threadIdx.x;
    double a = 0.0;
    for (int i = t; i < NPART; i += 256) a += partials[i];
    red[t] = a;
    __syncthreads();
    for (int off = 128; off > 0; off >>= 1) {
        if (t < off) red[t] += red[t + off];
        __syncthreads();
    }
    if (t == 0) out[0] = (float)(-red[0] / (double)PLANE);
}

extern "C" void kernel_launch(void* const* d_in, const int* in_sizes, int n_in,
                              void* d_out, int out_size, void* d_ws, size_t ws_size,
                              hipStream_t stream)
{
    const float* I = (const float*)d_in[0];
    const float* J = (const float*)d_in[1];
    float* out = (float*)d_out;

    double* partials = (double*)d_ws;
    const size_t part_bytes = (size_t)NPART * sizeof(double);
    float* F = (float*)((char*)d_ws + part_bytes);

    // Largest d-chunk (divisor of 192) whose 5-field buffer fits in ws.
    static const int divs[13] = {192,96,64,48,32,24,16,12,8,6,4,2,1};
    int CD = 1;
    for (int i = 0; i < 13; ++i) {
        size_t need = part_bytes + 5ull * (size_t)divs[i] * HWN * sizeof(float);
        if (need <= ws_size) { CD = divs[i]; break; }
    }

    for (int d0 = 0; d0 < DD; d0 += CD) {
        int d1 = d0 + CD;
        int nseg = (CD + SEG - 1) / SEG;
        dim3 g1(HWN / 256, nseg);
        k1_dsum<<<g1, dim3(256), 0, stream>>>(I, J, F, d0, d1, CD);
        k2_whsum<<<dim3(CD * NHC), dim3(192), 0, stream>>>(F, partials, d0, CD);
    }
    k3_reduce<<<dim3(1), dim3(256), 0, stream>>>(partials, out);
}

// Round 4
// 107.740 us; speedup vs baseline: 11.8733x; 1.4139x over previous
//
#include <hip/hip_runtime.h>

#define DD 192
#define HH 224
#define WW 192
#define HWN (HH*WW)              // 43008
#define PLANE ((size_t)DD*HWN)   // 8257536
#define DSEG 24                  // d outputs per kA block
#define TH 2                     // h rows per kA block
#define KA_THREADS 384           // TH * 192
#define HS 28                    // h outputs per kB block
#define NHS 8                    // 8 * 28 = 224
#define NPART (DD*NHS)           // 1536

// slab element loader for kA staging: i in [0,800) -> (field, row, col)
__device__ __forceinline__ float ld_slab(const float* __restrict__ I,
                                         const float* __restrict__ J,
                                         int din, int h0, int i)
{
    int f   = (i >= 400) ? 1 : 0;
    int rem = i - (f ? 400 : 0);
    int r   = (rem >= 200) ? 1 : 0;
    int c   = rem - (r ? 200 : 0);
    int wg  = c - 4;
    float v = 0.f;
    if (din >= 0 && din < DD && wg >= 0 && wg < WW) {
        const float* S = f ? J : I;
        v = S[(size_t)din * HWN + (size_t)(h0 + r) * WW + (size_t)wg];
    }
    return v;
}

// ---------------- kA: products + W-tap (LDS on I,J) + D-tap (reg ring) ----
// Writes 5 DW-summed fields. One __syncthreads per d-step, dbuf stage,
// prefetch into named regs (compiler-scheduled; NO inline asm).
__global__ __launch_bounds__(KA_THREADS) void kA(
    const float* __restrict__ I, const float* __restrict__ J,
    float* __restrict__ F, int chunk_base, int chunk)
{
    const int t  = threadIdx.x;
    const int h0 = blockIdx.x * TH;
    const int d0 = chunk_base + blockIdx.y * DSEG;

    __shared__ float stg[2][800];    // [buf][ field*400 + row*200 + col ]

    const int w    = t % 192;
    const int hl   = t / 192;
    const int hrow = h0 + hl;
    const size_t fs = (size_t)chunk * HWN;

    float r0[9], r1[9], r2[9], r3[9], r4[9];
    float S0=0.f,S1=0.f,S2=0.f,S3=0.f,S4=0.f;
#pragma unroll
    for (int k = 0; k < 9; ++k) { r0[k]=0.f; r1[k]=0.f; r2[k]=0.f; r3[k]=0.f; r4[k]=0.f; }

    // prologue: stage s=0 (din = d0-4) into buf 0
    {
        int din = d0 - 4;
        float p0 = ld_slab(I, J, din, h0, t);
        float p1 = ld_slab(I, J, din, h0, t + 384);
        float p2 = (t < 32) ? ld_slab(I, J, din, h0, t + 768) : 0.f;
        stg[0][t] = p0;
        stg[0][t + 384] = p1;
        if (t < 32) stg[0][t + 768] = p2;
    }
    __syncthreads();

    for (int bse = 0; bse < 36; bse += 9) {
#pragma unroll
        for (int k = 0; k < 9; ++k) {
            int s = bse + k;
            if (s < 32) {                       // uniform
                int din = d0 - 4 + s;

                // prefetch next slab (independent; loads issue early)
                float p0 = 0.f, p1 = 0.f, p2 = 0.f;
                if (s + 1 < 32) {
                    p0 = ld_slab(I, J, din + 1, h0, t);
                    p1 = ld_slab(I, J, din + 1, h0, t + 384);
                    if (t < 32) p2 = ld_slab(I, J, din + 1, h0, t + 768);
                }

                // W-tap from staged I,J: 18 LDS reads -> 5 window sums
                const float* sI = &stg[s & 1][hl * 200];
                const float* sJ = &stg[s & 1][400 + hl * 200];
                float a0=0.f,a1=0.f,a2=0.f,a3=0.f,a4=0.f;
#pragma unroll
                for (int j = 0; j < 9; ++j) {
                    float vi = sI[w + j], vj = sJ[w + j];
                    a0 += vi; a1 += vj; a2 += vi*vi; a3 += vj*vj; a4 += vi*vj;
                }

                // D-ring (static slot k)
                S0 += a0 - r0[k]; r0[k] = a0;
                S1 += a1 - r1[k]; r1[k] = a1;
                S2 += a2 - r2[k]; r2[k] = a2;
                S3 += a3 - r3[k]; r3[k] = a3;
                S4 += a4 - r4[k]; r4[k] = a4;

                int dc = din - 4;
                if (dc >= d0 && dc < d0 + DSEG) {   // uniform
                    size_t o = (size_t)(dc - chunk_base) * HWN
                             + (size_t)hrow * WW + (size_t)w;
                    F[o]        = S0;
                    F[fs + o]   = S1;
                    F[2*fs + o] = S2;
                    F[3*fs + o] = S3;
                    F[4*fs + o] = S4;
                }

                // store prefetched slab into the other buffer
                if (s + 1 < 32) {
                    float* dst = stg[(s + 1) & 1];
                    dst[t] = p0;
                    dst[t + 384] = p1;
                    if (t < 32) dst[t + 768] = p2;
                }
                __syncthreads();
            }
        }
    }
}

// ---------------- kB: H-tap (reg ring) + NCC math; no LDS in march --------
// thread owns (d,w), marches h. Coalesced loads of the 5 DW fields.
__global__ __launch_bounds__(192) void kB(
    const float* __restrict__ F, double* __restrict__ partials,
    int chunk_base, int chunk)
{
    const int drel = blockIdx.x;       // 0..chunk-1
    const int hs   = blockIdx.y;       // 0..NHS-1
    const int w    = threadIdx.x;      // 0..191
    const int h0   = hs * HS;
    const size_t fs = (size_t)chunk * HWN;
    const float* __restrict__ B = F + (size_t)drel * HWN + (size_t)w;

    float r0[9], r1[9], r2[9], r3[9], r4[9];
    float S0=0.f,S1=0.f,S2=0.f,S3=0.f,S4=0.f;
#pragma unroll
    for (int k = 0; k < 9; ++k) { r0[k]=0.f; r1[k]=0.f; r2[k]=0.f; r3[k]=0.f; r4[k]=0.f; }

    float acc = 0.f;

    // preload row for s=0 (hin = h0-4; always < HH)
    float c0=0.f,c1=0.f,c2=0.f,c3=0.f,c4=0.f;
    {
        int hin = h0 - 4;
        if (hin >= 0) {
            size_t o = (size_t)hin * WW;
            c0=B[o]; c1=B[fs+o]; c2=B[2*fs+o]; c3=B[3*fs+o]; c4=B[4*fs+o];
        }
    }

    for (int bse = 0; bse < 36; bse += 9) {
#pragma unroll
        for (int k = 0; k < 9; ++k) {
            int s = bse + k;

            // prefetch next row (uniform guard)
            float n0=0.f,n1=0.f,n2=0.f,n3=0.f,n4=0.f;
            int hin1 = h0 - 3 + s;
            if (s < 35 && hin1 >= 0 && hin1 < HH) {
                size_t o = (size_t)hin1 * WW;
                n0=B[o]; n1=B[fs+o]; n2=B[2*fs+o]; n3=B[3*fs+o]; n4=B[4*fs+o];
            }

            // H-ring (static slot k)
            S0 += c0 - r0[k]; r0[k] = c0;
            S1 += c1 - r1[k]; r1[k] = c1;
            S2 += c2 - r2[k]; r2[k] = c2;
            S3 += c3 - r3[k]; r3[k] = c3;
            S4 += c4 - r4[k]; r4[k] = c4;

            if (s >= 8) {
                const float inv = 1.0f / 729.0f;
                float cross = S4 - S0 * S1 * inv;
                float varI  = S2 - S0 * S0 * inv;
                float varJ  = S3 - S1 * S1 * inv;
                acc += cross * cross / (varI * varJ + 1e-5f);
            }

            c0=n0; c1=n1; c2=n2; c3=n3; c4=n4;
        }
    }

    __shared__ float red[192];
    red[w] = acc;
    __syncthreads();
#pragma unroll
    for (int off = 96; off >= 3; off >>= 1) {
        if (w < off) red[w] += red[w + off];
        __syncthreads();
    }
    if (w == 0) {
        int d = chunk_base + drel;
        partials[d * NHS + hs] = (double)(red[0] + red[1] + red[2]);
    }
}

// ---------------- k3: final reduction of 1536 partials --------------------
__global__ __launch_bounds__(256) void k3_reduce(
    const double* __restrict__ partials, float* __restrict__ out)
{
    __shared__ double red[256];
    int t = threadIdx.x;
    double a = 0.0;
    for (int i = t; i < NPART; i += 256) a += partials[i];
    red[t] = a;
    __syncthreads();
    for (int off = 128; off > 0; off >>= 1) {
        if (t < off) red[t] += red[t + off];
        __syncthreads();
    }
    if (t == 0) out[0] = (float)(-red[0] / (double)PLANE);
}

extern "C" void kernel_launch(void* const* d_in, const int* in_sizes, int n_in,
                              void* d_out, int out_size, void* d_ws, size_t ws_size,
                              hipStream_t stream)
{
    const float* I = (const float*)d_in[0];
    const float* J = (const float*)d_in[1];
    float* out = (float*)d_out;

    double* partials = (double*)d_ws;
    const size_t part_bytes = 16384;               // 1536*8 rounded up
    float* F = (float*)((char*)d_ws + part_bytes);

    // Largest d-chunk (multiple of DSEG, divisor of 192) fitting in ws.
    static const int chunks[4] = {192, 96, 48, 24};
    int chunk = 24;
    for (int i = 0; i < 4; ++i) {
        size_t need = part_bytes + 5ull * (size_t)chunks[i] * HWN * sizeof(float);
        if (need <= ws_size) { chunk = chunks[i]; break; }
    }

    for (int cb = 0; cb < DD; cb += chunk) {
        kA<<<dim3(HH / TH, chunk / DSEG), dim3(KA_THREADS), 0, stream>>>(
            I, J, F, cb, chunk);
        kB<<<dim3(chunk, NHS), dim3(192), 0, stream>>>(F, partials, cb, chunk);
    }
    k3_reduce<<<dim3(1), dim3(256), 0, stream>>>(partials, out);
}

// Round 5
// 78.579 us; speedup vs baseline: 16.2796x; 1.3711x over previous
//
#include <hip/hip_runtime.h>

#define DD 192
#define HH 224
#define WW 192
#define HWN (HH*WW)              // 43008
#define PLANE ((size_t)DD*HWN)   // 8257536
#define DSEG 32                  // d outputs per kA block
#define HS 28                    // h outputs per kB block
#define NHS 8                    // 8 * 28 = 224
#define NPART (DD*NHS)           // 1536

// ---------------- kA: products + W-tap + D-tap, BARRIER-FREE --------------
// Each 64-lane wave owns (h, 64-col w-group) and marches d. It stages a
// 72-col slab of I and J in WAVE-PRIVATE LDS (intra-wave ordering via
// lgkmcnt only — no __syncthreads in the march), does the 9-tap W-window
// from LDS, forms the 5 products' window sums in-register, then a 9-deep
// D-ring (static slots) and writes the 5 DW-summed fields coalesced.
__global__ __launch_bounds__(192) void kA(
    const float* __restrict__ I, const float* __restrict__ J,
    float* __restrict__ F, int chunk_base, int chunk)
{
    const int h  = blockIdx.x;                 // 0..223
    const int d0 = chunk_base + blockIdx.y * DSEG;
    const int wv = threadIdx.x >> 6;           // 0..2
    const int l  = threadIdx.x & 63;
    const int w0 = wv << 6;

    __shared__ float stg[3][2][2][72];         // [wave][buf][field][slot]
    float (*st)[2][72] = stg[wv];              // wave-private view

    // pre-zero this wave's slots once; masked lanes never overwrite pads
#pragma unroll
    for (int b = 0; b < 2; ++b) {
        st[b][0][l] = 0.f; st[b][1][l] = 0.f;
        if (l < 8) { st[b][0][64 + l] = 0.f; st[b][1][64 + l] = 0.f; }
    }
    // no sync: nothing crosses waves

    const size_t fs   = (size_t)chunk * HWN;
    const size_t rowb = (size_t)h * WW;
    const int  cm = w0 - 4 + l;                // main staged col -> slot l
    const int  ch = w0 + 60 + l;               // halo staged col -> slot 64+l
    const bool vm = (cm >= 0) && (cm < WW);
    const bool vh = (l < 8) && (ch < WW);

    float r0[9], r1[9], r2[9], r3[9], r4[9];
    float S0=0.f,S1=0.f,S2=0.f,S3=0.f,S4=0.f;
#pragma unroll
    for (int k = 0; k < 9; ++k) { r0[k]=0.f; r1[k]=0.f; r2[k]=0.f; r3[k]=0.f; r4[k]=0.f; }

    for (int bse = 0; bse < 54; bse += 18) {   // runtime outer: no code bloat
#pragma unroll
        for (int k = 0; k < 18; ++k) {
            int s = bse + k;
            if (s < DSEG + 8) {                // uniform
                const int slot = (k < 9) ? k : k - 9;   // compile-time
                const int buf  = k & 1;                 // compile-time
                int din = d0 - 4 + s;
                float a0, a1, a2, a3, a4;
                if (din >= 0 && din < DD) {    // uniform per wave
                    const float* Ip = I + (size_t)din * HWN + rowb;
                    const float* Jp = J + (size_t)din * HWN + rowb;
                    if (vm) {
                        st[buf][0][l] = Ip[cm];
                        st[buf][1][l] = Jp[cm];
                    }
                    if (vh) {
                        st[buf][0][64 + l] = Ip[ch];
                        st[buf][1][64 + l] = Jp[ch];
                    }
                    a0=a1=a2=a3=a4=0.f;
#pragma unroll
                    for (int j = 0; j < 9; ++j) {
                        float vi = st[buf][0][l + j];
                        float vj = st[buf][1][l + j];
                        a0 += vi;
                        a1 += vj;
                        a2 = fmaf(vi, vi, a2);
                        a3 = fmaf(vj, vj, a3);
                        a4 = fmaf(vi, vj, a4);
                    }
                } else {
                    a0=a1=a2=a3=a4=0.f;        // zero-pad plane
                }
                S0 += a0 - r0[slot]; r0[slot] = a0;
                S1 += a1 - r1[slot]; r1[slot] = a1;
                S2 += a2 - r2[slot]; r2[slot] = a2;
                S3 += a3 - r3[slot]; r3[slot] = a3;
                S4 += a4 - r4[slot]; r4[slot] = a4;

                int dc = din - 4;
                if (dc >= d0 && dc < d0 + DSEG) {       // uniform
                    size_t o = (size_t)(dc - chunk_base) * HWN + rowb
                             + (size_t)(w0 + l);
                    F[o]        = S0;
                    F[fs + o]   = S1;
                    F[2*fs + o] = S2;
                    F[3*fs + o] = S3;
                    F[4*fs + o] = S4;
                }
            }
        }
    }
}

// ---------------- kB: H-tap (reg ring) + NCC math; no LDS in march --------
__global__ __launch_bounds__(192) void kB(
    const float* __restrict__ F, double* __restrict__ partials,
    int chunk_base, int chunk)
{
    const int drel = blockIdx.x;
    const int hs   = blockIdx.y;
    const int w    = threadIdx.x;
    const int h0   = hs * HS;
    const size_t fs = (size_t)chunk * HWN;
    const float* __restrict__ B = F + (size_t)drel * HWN + (size_t)w;

    float r0[9], r1[9], r2[9], r3[9], r4[9];
    float S0=0.f,S1=0.f,S2=0.f,S3=0.f,S4=0.f;
#pragma unroll
    for (int k = 0; k < 9; ++k) { r0[k]=0.f; r1[k]=0.f; r2[k]=0.f; r3[k]=0.f; r4[k]=0.f; }

    float acc = 0.f;

    float c0=0.f,c1=0.f,c2=0.f,c3=0.f,c4=0.f;
    {
        int hin = h0 - 4;
        if (hin >= 0) {
            size_t o = (size_t)hin * WW;
            c0=B[o]; c1=B[fs+o]; c2=B[2*fs+o]; c3=B[3*fs+o]; c4=B[4*fs+o];
        }
    }

    for (int bse = 0; bse < 36; bse += 9) {
#pragma unroll
        for (int k = 0; k < 9; ++k) {
            int s = bse + k;

            float n0=0.f,n1=0.f,n2=0.f,n3=0.f,n4=0.f;
            int hin1 = h0 - 3 + s;
            if (s < 35 && hin1 >= 0 && hin1 < HH) {
                size_t o = (size_t)hin1 * WW;
                n0=B[o]; n1=B[fs+o]; n2=B[2*fs+o]; n3=B[3*fs+o]; n4=B[4*fs+o];
            }

            S0 += c0 - r0[k]; r0[k] = c0;
            S1 += c1 - r1[k]; r1[k] = c1;
            S2 += c2 - r2[k]; r2[k] = c2;
            S3 += c3 - r3[k]; r3[k] = c3;
            S4 += c4 - r4[k]; r4[k] = c4;

            if (s >= 8) {
                const float inv = 1.0f / 729.0f;
                float cross = S4 - S0 * S1 * inv;
                float varI  = S2 - S0 * S0 * inv;
                float varJ  = S3 - S1 * S1 * inv;
                acc += cross * cross / (varI * varJ + 1e-5f);
            }

            c0=n0; c1=n1; c2=n2; c3=n3; c4=n4;
        }
    }

    __shared__ float red[192];
    red[w] = acc;
    __syncthreads();
#pragma unroll
    for (int off = 96; off >= 3; off >>= 1) {
        if (w < off) red[w] += red[w + off];
        __syncthreads();
    }
    if (w == 0) {
        int d = chunk_base + drel;
        partials[d * NHS + hs] = (double)(red[0] + red[1] + red[2]);
    }
}

// ---------------- k3: final reduction of 1536 partials --------------------
__global__ __launch_bounds__(256) void k3_reduce(
    const double* __restrict__ partials, float* __restrict__ out)
{
    __shared__ double red[256];
    int t = threadIdx.x;
    double a = 0.0;
    for (int i = t; i < NPART; i += 256) a += partials[i];
    red[t] = a;
    __syncthreads();
    for (int off = 128; off > 0; off >>= 1) {
        if (t < off) red[t] += red[t + off];
        __syncthreads();
    }
    if (t == 0) out[0] = (float)(-red[0] / (double)PLANE);
}

extern "C" void kernel_launch(void* const* d_in, const int* in_sizes, int n_in,
                              void* d_out, int out_size, void* d_ws, size_t ws_size,
                              hipStream_t stream)
{
    const float* I = (const float*)d_in[0];
    const float* J = (const float*)d_in[1];
    float* out = (float*)d_out;

    double* partials = (double*)d_ws;
    const size_t part_bytes = 16384;               // 1536*8 rounded up
    float* F = (float*)((char*)d_ws + part_bytes);

    // Largest d-chunk (multiple of DSEG, divisor of 192) fitting in ws.
    static const int chunks[4] = {192, 96, 64, 32};
    int chunk = 32;
    for (int i = 0; i < 4; ++i) {
        size_t need = part_bytes + 5ull * (size_t)chunks[i] * HWN * sizeof(float);
        if (need <= ws_size) { chunk = chunks[i]; break; }
    }

    for (int cb = 0; cb < DD; cb += chunk) {
        kA<<<dim3(HH, chunk / DSEG), dim3(192), 0, stream>>>(I, J, F, cb, chunk);
        kB<<<dim3(chunk, NHS), dim3(192), 0, stream>>>(F, partials, cb, chunk);
    }
    k3_reduce<<<dim3(1), dim3(256), 0, stream>>>(partials, out);
}